// Round 1
// baseline (1103.065 us; speedup 1.0000x reference)
//
#include <hip/hip_runtime.h>
#include <cstdint>
#include <cstddef>

// MPNN: 4 edge-conv layers + head MLP.  N=50000 nodes, E=800000 edges, F=64.
// Strategy: f16 MFMA (16x16x32, fp32 acc) for edge GEMMs; fp32 scatter/mean/bias.
// Each wave owns 16 edges -> all LDS H-tile traffic is wave-private (no barriers
// in the K loop).  W1 staged in LDS in B-fragment order; W2 frags in VGPRs.

#define NN 50000
#define NE 800000

typedef _Float16 f16;
typedef _Float16 f16x8 __attribute__((ext_vector_type(8)));
typedef float    f32x4 __attribute__((ext_vector_type(4)));

// ---------------------------------------------------------------- small kernels
__global__ void count_kernel(const int* __restrict__ eidx, int* __restrict__ cnt) {
  int i = blockIdx.x * 256 + threadIdx.x;
  if (i < NE) atomicAdd(&cnt[eidx[i]], 1);
}

__global__ void inv_kernel(const int* __restrict__ cnt, float* __restrict__ inv) {
  int v = blockIdx.x * 256 + threadIdx.x;
  if (v < NN) { int c = cnt[v]; inv[v] = 1.0f / (float)(c > 0 ? c : 1); }
}

// mean + relu + re-zero accumulator (so next conv starts from 0)
template<int F32OUT>
__global__ void node_mean_kernel(float* __restrict__ s, const float* __restrict__ inv,
                                 void* __restrict__ xout) {
  int i = blockIdx.x * 256 + threadIdx.x;   // grid covers NN*64 exactly
  float v = fmaxf(s[i] * inv[i >> 6], 0.0f);
  if (F32OUT) ((float*)xout)[i] = v;
  else        ((f16*)xout)[i]   = (f16)v;
  s[i] = 0.0f;
}

// ---------------------------------------------------------------- edge conv
// CONV=1: K=9  (pad 32),  h=[na[r](3), na[c](3), ea(3)]
// CONV=2: K=195(pad 224), h=[x1[r](64), x1[c](64), e1(64), ea(3)]
// CONV=3: K=384,          h=[x2[r],x1[r], x2[c],x1[c], e2,e1]  (64 each)
// CONV=4: K=384,          h=[x3[r],x2[r], x3[c],x2[c], e3,e2]
template<int CONV>
__global__ __launch_bounds__(256, 2) void edge_conv_kernel(
    const int*   __restrict__ eidx,
    const float* __restrict__ na,
    const f16*   __restrict__ xA, const f16* __restrict__ xB,
    const f16*   __restrict__ eA, const f16* __restrict__ eB,
    const float* __restrict__ ea,
    const float* __restrict__ W1, const float* __restrict__ b1,
    const float* __restrict__ W2, const float* __restrict__ b2,
    float* __restrict__ s,
    f16* __restrict__ eout_h, float* __restrict__ eout_f)
{
  constexpr int K1REAL = (CONV == 1) ? 9 : (CONV == 2 ? 195 : 384);
  constexpr int KSTEPS = (CONV == 1) ? 1 : (CONV == 2 ? 7 : 12);   // K/32
  constexpr int NCHUNK = (CONV == 1) ? 1 : (CONV == 2 ? 4 : 6);    // 64-col chunks
  constexpr int NTILES = NE / 64;
  constexpr int HS = 88;  // H row stride (f16): 176B -> 2-way bank aliasing (free)

  __shared__ f16   w1f[KSTEPS * 4 * 64 * 8];   // B-fragment order
  __shared__ f16   buf[64 * HS];               // H chunk / hidden (wave-private rows)
  __shared__ float b1s[64], b2s[64];
  __shared__ int   ridx[64], cidx[64];

  const int tid  = threadIdx.x;
  const int lane = tid & 63;
  const int wv   = tid >> 6;
  const int quad = lane >> 4;
  const int l15  = lane & 15;

  // ---- stage W1 into LDS in fragment order: frag(ks,t,lane)[j] = W1[ks*32+quad*8+j][t*16+l15]
  for (int u = tid; u < KSTEPS * 256; u += 256) {
    int l = u & 63, t = (u >> 6) & 3, ks = u >> 8;
    int n = t * 16 + (l & 15);
    int kb = ks * 32 + ((l >> 4) * 8);
    f16x8 v;
#pragma unroll
    for (int j = 0; j < 8; ++j) {
      int k = kb + j;
      v[j] = (f16)((k < K1REAL) ? W1[k * 64 + n] : 0.0f);
    }
    *(f16x8*)&w1f[u * 8] = v;
  }
  if (tid < 64) b1s[tid] = b1[tid];
  else if (tid < 128) b2s[tid - 64] = b2[tid - 64];

  // ---- W2 fragments in registers
  f16x8 w2r[2][4];
#pragma unroll
  for (int ks = 0; ks < 2; ++ks)
#pragma unroll
    for (int t = 0; t < 4; ++t) {
      int n = t * 16 + l15;
      int kb = ks * 32 + quad * 8;
#pragma unroll
      for (int j = 0; j < 8; ++j) w2r[ks][t][j] = (f16)W2[(kb + j) * 64 + n];
    }

  for (int tile = blockIdx.x; tile < NTILES; tile += gridDim.x) {
    const int ebase = tile * 64;
    __syncthreads();                         // everyone done with prev ridx/cidx
    if (tid < 64)       ridx[tid]      = eidx[ebase + tid];
    else if (tid < 128) cidx[tid - 64] = eidx[NE + ebase + tid - 64];
    __syncthreads();                         // indices (+w1f on first iter) visible

    f32x4 acc[4];
#pragma unroll
    for (int t = 0; t < 4; ++t) acc[t] = (f32x4){0.f, 0.f, 0.f, 0.f};

    for (int c = 0; c < NCHUNK; ++c) {
      // ---- stage chunk c (each thread writes rows of its OWN wave: e = tid>>2)
      if constexpr (CONV == 1) {
        int e = tid >> 2, q = tid & 3, eg = ebase + e;
        f16x8 v;
#pragma unroll
        for (int j = 0; j < 8; ++j) v[j] = (f16)0.0f;
        if (q == 0) {
          int r = ridx[e], cc = cidx[e];
          v[0] = (f16)na[r*3];  v[1] = (f16)na[r*3+1];  v[2] = (f16)na[r*3+2];
          v[3] = (f16)na[cc*3]; v[4] = (f16)na[cc*3+1]; v[5] = (f16)na[cc*3+2];
          v[6] = (f16)ea[eg*3]; v[7] = (f16)ea[eg*3+1];
        } else if (q == 1) {
          v[0] = (f16)ea[eg*3+2];
        }
        *(f16x8*)&buf[e * HS + q * 8] = v;
      } else if (CONV == 2 && c == 3) {      // tail: ea(3) + zero pad to col 224
        int e = tid >> 2, q = tid & 3;
        f16x8 v;
#pragma unroll
        for (int j = 0; j < 8; ++j) v[j] = (f16)0.0f;
        if (q == 0) {
          int eg = ebase + e;
          v[0] = (f16)ea[eg*3]; v[1] = (f16)ea[eg*3+1]; v[2] = (f16)ea[eg*3+2];
        }
        *(f16x8*)&buf[e * HS + q * 8] = v;
      } else {
#pragma unroll
        for (int i = 0; i < 2; ++i) {
          int u = tid * 2 + i;
          int e = u >> 3, part = u & 7;
          const f16* p;
          if constexpr (CONV == 2) {
            p = (c == 0) ? (xA + (size_t)ridx[e] * 64)
              : (c == 1) ? (xA + (size_t)cidx[e] * 64)
                         : (eA + (size_t)(ebase + e) * 64);
          } else {
            p = (c == 0) ? (xA + (size_t)ridx[e] * 64)
              : (c == 1) ? (xB + (size_t)ridx[e] * 64)
              : (c == 2) ? (xA + (size_t)cidx[e] * 64)
              : (c == 3) ? (xB + (size_t)cidx[e] * 64)
              : (c == 4) ? (eA + (size_t)(ebase + e) * 64)
                         : (eB + (size_t)(ebase + e) * 64);
          }
          *(uint4*)&buf[e * HS + part * 8] = *(const uint4*)(p + part * 8);
        }
      }
      // ---- MFMA over this chunk's k-steps (wave-private rows; DS in-order per wave)
      int ks0 = c * 2;
      int nks = (KSTEPS - ks0 >= 2) ? 2 : 1;
      for (int kk = 0; kk < nks; ++kk) {
        f16x8 a = *(f16x8*)&buf[(wv * 16 + l15) * HS + kk * 32 + quad * 8];
        int ks = ks0 + kk;
#pragma unroll
        for (int t = 0; t < 4; ++t) {
          f16x8 b = *(f16x8*)&w1f[((ks * 4 + t) * 64 + lane) * 8];
          acc[t] = __builtin_amdgcn_mfma_f32_16x16x32_f16(a, b, acc[t], 0, 0, 0);
        }
      }
    }

    // ---- bias + relu -> hidden (same wave-private rows of buf)
#pragma unroll
    for (int t = 0; t < 4; ++t) {
      int n = t * 16 + l15;
      float bb = b1s[n];
#pragma unroll
      for (int r = 0; r < 4; ++r) {
        int m = wv * 16 + quad * 4 + r;
        buf[m * HS + n] = (f16)fmaxf(acc[t][r] + bb, 0.0f);
      }
    }

    // ---- GEMM2: [16,64] x [64,64]
    f32x4 acc2[4];
#pragma unroll
    for (int t = 0; t < 4; ++t) acc2[t] = (f32x4){0.f, 0.f, 0.f, 0.f};
#pragma unroll
    for (int kk = 0; kk < 2; ++kk) {
      f16x8 a = *(f16x8*)&buf[(wv * 16 + l15) * HS + kk * 32 + quad * 8];
#pragma unroll
      for (int t = 0; t < 4; ++t)
        acc2[t] = __builtin_amdgcn_mfma_f32_16x16x32_f16(a, w2r[kk][t], acc2[t], 0, 0, 0);
    }

    // ---- epilogue: scatter raw edge_out, store relu(edge_out)
#pragma unroll
    for (int t = 0; t < 4; ++t) {
      int n = t * 16 + l15;
      float bb = b2s[n];
#pragma unroll
      for (int r = 0; r < 4; ++r) {
        int m = wv * 16 + quad * 4 + r;
        float val = acc2[t][r] + bb;
        int eg = ebase + m;
        atomicAdd(&s[(size_t)ridx[m] * 64 + n], val);
        if (CONV < 4) eout_h[(size_t)eg * 64 + n] = (f16)fmaxf(val, 0.0f);
        else          eout_f[(size_t)eg * 64 + n] = fmaxf(val, 0.0f);
      }
    }
  }
}

// ---------------------------------------------------------------- head MLP
__global__ void head_kernel(const float* __restrict__ x4,
                            const float* __restrict__ W1, const float* __restrict__ b1,
                            const float* __restrict__ W2, const float* __restrict__ b2,
                            float* __restrict__ out) {
  __shared__ float xs[4][64];
  __shared__ float hs[4][64];
  int tid = threadIdx.x;
  int i = tid >> 6, f = tid & 63;
  int nb = blockIdx.x * 4;
  xs[i][f] = x4[(size_t)(nb + i) * 64 + f];
  __syncthreads();
  float h = b1[f];
#pragma unroll
  for (int k = 0; k < 64; ++k) h += xs[i][k] * W1[k * 64 + f];
  hs[i][f] = fmaxf(h, 0.0f);
  __syncthreads();
  if (tid < 12) {
    int ii = tid >> 2;          // wrong mapping would skip nodes; use /3 %3:
    ii = tid / 3; int j = tid % 3;
    float o = b2[j];
#pragma unroll
    for (int k = 0; k < 64; ++k) o += hs[ii][k] * W2[k * 3 + j];
    out[(size_t)(nb + ii) * 3 + j] = o;
  }
}

// ---------------------------------------------------------------- launch
extern "C" void kernel_launch(void* const* d_in, const int* in_sizes, int n_in,
                              void* d_out, int out_size, void* d_ws, size_t ws_size,
                              hipStream_t stream) {
  const float* na   = (const float*)d_in[0];
  const float* ea   = (const float*)d_in[1];
  const int*   eidx = (const int*)d_in[2];
  const float* c1W1 = (const float*)d_in[3];
  const float* c1b1 = (const float*)d_in[4];
  const float* c1W2 = (const float*)d_in[5];
  const float* c1b2 = (const float*)d_in[6];
  const float* c2W1 = (const float*)d_in[7];
  const float* c2b1 = (const float*)d_in[8];
  const float* c2W2 = (const float*)d_in[9];
  const float* c2b2 = (const float*)d_in[10];
  const float* c3W1 = (const float*)d_in[11];
  const float* c3b1 = (const float*)d_in[12];
  const float* c3W2 = (const float*)d_in[13];
  const float* c3b2 = (const float*)d_in[14];
  const float* c4W1 = (const float*)d_in[15];
  const float* c4b1 = (const float*)d_in[16];
  const float* c4W2 = (const float*)d_in[17];
  const float* c4b2 = (const float*)d_in[18];
  const float* mW1  = (const float*)d_in[19];
  const float* mb1  = (const float*)d_in[20];
  const float* mW2  = (const float*)d_in[21];
  const float* mb2  = (const float*)d_in[22];

  char* ws = (char*)d_ws;
  size_t off = 0;
  auto alloc = [&](size_t b) -> void* {
    void* p = ws + off;
    off += (b + 255) & ~(size_t)255;
    return p;
  };
  float* s   = (float*)alloc((size_t)NN * 64 * 4);   // 12.8 MB scatter accumulator
  float* inv = (float*)alloc((size_t)NN * 4);
  int*   cnt = (int*)  alloc((size_t)NN * 4);
  f16*   x1  = (f16*)  alloc((size_t)NN * 64 * 2);
  f16*   x2  = (f16*)  alloc((size_t)NN * 64 * 2);
  f16*   x3  = (f16*)  alloc((size_t)NN * 64 * 2);
  float* x4  = (float*)alloc((size_t)NN * 64 * 4);
  f16*   e1  = (f16*)  alloc((size_t)NE * 64 * 2);   // 102.4 MB each
  f16*   e2  = (f16*)  alloc((size_t)NE * 64 * 2);
  f16*   e3  = (f16*)  alloc((size_t)NE * 64 * 2);
  // total ~353 MB of workspace

  float* out_x = (float*)d_out;
  float* out_e = out_x + (size_t)NN * 3;

  hipMemsetAsync(s, 0, (size_t)NN * 64 * 4, stream);
  hipMemsetAsync(cnt, 0, (size_t)NN * 4, stream);
  count_kernel<<<NE / 256, 256, 0, stream>>>(eidx, cnt);
  inv_kernel<<<(NN + 255) / 256, 256, 0, stream>>>(cnt, inv);

  edge_conv_kernel<1><<<512, 256, 0, stream>>>(eidx, na, nullptr, nullptr, nullptr, nullptr,
                                               ea, c1W1, c1b1, c1W2, c1b2, s, e1, nullptr);
  node_mean_kernel<0><<<NN * 64 / 256, 256, 0, stream>>>(s, inv, x1);

  edge_conv_kernel<2><<<512, 256, 0, stream>>>(eidx, nullptr, x1, nullptr, e1, nullptr,
                                               ea, c2W1, c2b1, c2W2, c2b2, s, e2, nullptr);
  node_mean_kernel<0><<<NN * 64 / 256, 256, 0, stream>>>(s, inv, x2);

  edge_conv_kernel<3><<<512, 256, 0, stream>>>(eidx, nullptr, x2, x1, e2, e1,
                                               nullptr, c3W1, c3b1, c3W2, c3b2, s, e3, nullptr);
  node_mean_kernel<0><<<NN * 64 / 256, 256, 0, stream>>>(s, inv, x3);

  edge_conv_kernel<4><<<512, 256, 0, stream>>>(eidx, nullptr, x3, x2, e3, e2,
                                               nullptr, c4W1, c4b1, c4W2, c4b2, s, nullptr, out_e);
  node_mean_kernel<1><<<NN * 64 / 256, 256, 0, stream>>>(s, inv, x4);

  head_kernel<<<NN / 4, 256, 0, stream>>>(x4, mW1, mb1, mW2, mb2, out_x);
}